// Round 7
// baseline (300.110 us; speedup 1.0000x reference)
//
#include <hip/hip_runtime.h>
#include <hip/hip_bf16.h>

// Problem constants (fixed by the reference):
//   N=100000, E=500000, V=50000, NE=1000000, D=300, C=20, NG=512
#define NG 512
#define D_DIM 300
#define C_DIM 20
#define NSLICE 16
#define NBINS (NSLICE * NG)   // 8192
#define CH 256                // edges per accum chunk (R3-proven)
#define BPS 128               // blocks per slice per phase
#define SC_EPB 1024           // edges per scatter block

// ---------------- K1: in-degree + (vslice,g) histogram ----------------
__global__ __launch_bounds__(1024) void count_hist(const int* __restrict__ dst,
                                                   const int* __restrict__ src,
                                                   const int* __restrict__ nodes_batch,
                                                   const int* __restrict__ graph_ids,
                                                   int* __restrict__ cnt,
                                                   int* __restrict__ kcnt,
                                                   int E, int KS) {
    __shared__ int h[NBINS];
    int t = threadIdx.x;
    for (int i = t; i < NBINS; i += 1024) h[i] = 0;
    __syncthreads();
    for (int e = blockIdx.x * 1024 + t; e < E; e += gridDim.x * 1024) {
        int d = dst[e];
        atomicAdd(&cnt[d], 1);
        int v = nodes_batch[src[e]];
        int g = graph_ids[d];
        atomicAdd(&h[(v / KS) * NG + g], 1);
    }
    __syncthreads();
    for (int i = t; i < NBINS; i += 1024)
        if (h[i]) atomicAdd(&kcnt[i], h[i]);
}

// ---------------- K2: exclusive scan of 8192 bins (single block) ----------------
__global__ __launch_bounds__(1024) void scan8k(const int* __restrict__ kcnt,
                                               int* __restrict__ koff,
                                               int* __restrict__ kfill, int E) {
    __shared__ int s[1024];
    int t = threadIdx.x;
    int loc[8];
    int sum = 0;
#pragma unroll
    for (int i = 0; i < 8; i++) { loc[i] = sum; sum += kcnt[t * 8 + i]; }
    s[t] = sum;
    __syncthreads();
    for (int off = 1; off < 1024; off <<= 1) {
        int x = (t >= off) ? s[t - off] : 0;
        __syncthreads();
        s[t] += x;
        __syncthreads();
    }
    int base = s[t] - sum;
#pragma unroll
    for (int i = 0; i < 8; i++) {
        int val = base + loc[i];
        koff[t * 8 + i] = val;
        kfill[t * 8 + i] = val;
    }
    if (t == 1023) koff[NBINS] = E;
}

// ---------------- K3: scatter edges into (vslice,g)-sorted list ----------------
__global__ __launch_bounds__(256) void scatter8k(const int* __restrict__ src,
                                                 const int* __restrict__ dst,
                                                 const int* __restrict__ eb,
                                                 const int* __restrict__ nodes_batch,
                                                 const float* __restrict__ edge_embed,
                                                 const int* __restrict__ graph_ids,
                                                 const int* __restrict__ cnt,
                                                 int* __restrict__ kfill,
                                                 int2* __restrict__ elist, int E, int KS) {
    __shared__ int bcnt[NBINS];
    __shared__ int base[NBINS];
    int t = threadIdx.x;
    int e0 = blockIdx.x * SC_EPB;
    for (int i = t; i < NBINS; i += 256) bcnt[i] = 0;
    __syncthreads();
    int vs[SC_EPB / 256];
    float scales[SC_EPB / 256];
    int keys[SC_EPB / 256];
#pragma unroll
    for (int k = 0; k < SC_EPB / 256; k++) {
        int e = e0 + k * 256 + t;
        keys[k] = -1;
        if (e < E) {
            int d = dst[e];
            int v = nodes_batch[src[e]];
            keys[k] = (v / KS) * NG + graph_ids[d];
            vs[k] = v;
            scales[k] = edge_embed[eb[e]] / (float)max(cnt[d], 1);
            atomicAdd(&bcnt[keys[k]], 1);
        }
    }
    __syncthreads();
    for (int i = t; i < NBINS; i += 256) {
        int c = bcnt[i];
        base[i] = c ? atomicAdd(&kfill[i], c) : 0;
        bcnt[i] = 0;
    }
    __syncthreads();
#pragma unroll
    for (int k = 0; k < SC_EPB / 256; k++) {
        if (keys[k] >= 0) {
            int pos = base[keys[k]] + atomicAdd(&bcnt[keys[k]], 1);
            elist[pos] = make_int2(vs[k], __float_as_int(scales[k]));
        }
    }
}

// ---------------- K4: sliced accumulate, R3-style inner loop ----------------
// phase p: slice = (bid&7) + 8p pinned to XCD bid&7; j0 = bid>>3 picks the chunk.
// 320 threads = 4 edge-subgroups x 80 lanes (lane owns 4 dims, float4 gather).
// Register accumulate per segment, fire-and-forget gacc atomics, no barriers
// in the segment loop.
__global__ __launch_bounds__(320) void accum_slice(const int2* __restrict__ elist,
                                                   const int* __restrict__ koff,
                                                   const float* __restrict__ Bmat,
                                                   float* __restrict__ gacc, int phase) {
    __shared__ int2 tile[CH];
    __shared__ int soff[NG + 1];
    int t = threadIdx.x;
    int slice = (blockIdx.x & 7) + 8 * phase;
    int j0 = blockIdx.x >> 3;
    for (int i = t; i <= NG; i += 320) soff[i] = koff[slice * NG + i];
    __syncthreads();
    int sbeg = soff[0], send = soff[NG];
    int nch = (send - sbeg + CH - 1) / CH;
    int sub = t / 80;
    int lane = t % 80;
    bool act = lane < 75;   // 75*4 = 300

    for (int cj = j0; cj < nch; cj += BPS) {
        int c0 = sbeg + cj * CH;
        int m = min(CH, send - c0);
        __syncthreads();
        for (int i = t; i < m; i += 320) tile[i] = elist[c0 + i];
        __syncthreads();
        // largest bl with soff[bl] <= c0 (uniform across block)
        int lo = 0, hi = NG - 1;
        while (lo < hi) {
            int mid = (lo + hi + 1) >> 1;
            if (soff[mid] <= c0) lo = mid; else hi = mid - 1;
        }
        int bl = lo;
        int j = 0;
        while (j < m) {
            while (soff[bl + 1] <= c0 + j) bl++;
            int end = min(m, soff[bl + 1] - c0);
            float ax = 0.f, ay = 0.f, az = 0.f, aw = 0.f;
            if (act) {
#pragma unroll 8
                for (int jj = j + sub; jj < end; jj += 4) {
                    int2 pr = tile[jj];
                    float s = __int_as_float(pr.y);
                    float4 v = ((const float4*)(Bmat + (size_t)pr.x * D_DIM))[lane];
                    ax += s * v.x; ay += s * v.y; az += s * v.z; aw += s * v.w;
                }
                float* dest = gacc + bl * D_DIM + lane * 4;
                atomicAdd(dest + 0, ax);
                atomicAdd(dest + 1, ay);
                atomicAdd(dest + 2, az);
                atomicAdd(dest + 3, aw);
            }
            j = end;
        }
    }
}

// ---------------- K5: per-graph ReLU + FC ----------------
__global__ __launch_bounds__(320) void fc_kernel(const float* __restrict__ gacc,
                                                 const float* __restrict__ fc_w,
                                                 const float* __restrict__ fc_b,
                                                 float* __restrict__ out) {
    __shared__ float wlds[D_DIM * C_DIM];
    __shared__ float accs[D_DIM];
    __shared__ float outs[C_DIM];
    int gid = blockIdx.x;
    int t = threadIdx.x;
    for (int i = t; i < D_DIM * C_DIM; i += 320) wlds[i] = fc_w[i];
    if (t < D_DIM) accs[t] = gacc[gid * D_DIM + t];
    if (t < C_DIM) outs[t] = fc_b[t];
    __syncthreads();
    if (t < C_DIM * 12) {
        int c = t % C_DIM;
        int ch = t / C_DIM;
        float p = 0.f;
#pragma unroll
        for (int d = ch * 25; d < ch * 25 + 25; d++) {
            float gv = accs[d];
            gv = gv > 0.f ? gv : 0.f;
            p += gv * wlds[d * C_DIM + c];
        }
        atomicAdd(&outs[c], p);
    }
    __syncthreads();
    if (t < C_DIM) out[gid * C_DIM + t] = outs[t];
}

extern "C" void kernel_launch(void* const* d_in, const int* in_sizes, int n_in,
                              void* d_out, int out_size, void* d_ws, size_t ws_size,
                              hipStream_t stream) {
    const int* nodes_batch = (const int*)d_in[0];
    const int* edges_batch = (const int*)d_in[1];
    const int* src = (const int*)d_in[2];
    const int* dst = (const int*)d_in[3];
    const int* graph_ids = (const int*)d_in[4];
    const float* node_embed = (const float*)d_in[5];
    const float* edge_embed = (const float*)d_in[6];
    const float* fc_w = (const float*)d_in[7];
    const float* fc_b = (const float*)d_in[8];
    float* out = (float*)d_out;

    int N = in_sizes[0];
    int E = in_sizes[2];
    int K = in_sizes[5] / D_DIM;   // vocab size V
    int KS = (K + NSLICE - 1) / NSLICE;

    char* ws = (char*)d_ws;
    size_t off = 0;
    int* cnt = (int*)(ws + off); off += (size_t)N * 4;
    int* kcnt = (int*)(ws + off); off += (size_t)NBINS * 4;
    int* koff = (int*)(ws + off); off += (size_t)(NBINS + 1) * 4;
    int* kfill = (int*)(ws + off); off += (size_t)NBINS * 4;
    float* gacc = (float*)(ws + off); off += (size_t)NG * D_DIM * 4;
    off = (off + 15) & ~(size_t)15;
    size_t need = off + (size_t)E * 8;

    if (ws_size >= need) {
        int2* elist = (int2*)(ws + off);
        hipMemsetAsync(cnt, 0, (size_t)N * 4, stream);
        hipMemsetAsync(kcnt, 0, (size_t)NBINS * 4, stream);
        hipMemsetAsync(gacc, 0, (size_t)NG * D_DIM * 4, stream);
        count_hist<<<256, 1024, 0, stream>>>(dst, src, nodes_batch, graph_ids, cnt, kcnt, E, KS);
        scan8k<<<1, 1024, 0, stream>>>(kcnt, koff, kfill, E);
        int nsb = (E + SC_EPB - 1) / SC_EPB;
        scatter8k<<<nsb, 256, 0, stream>>>(src, dst, edges_batch, nodes_batch, edge_embed,
                                           graph_ids, cnt, kfill, elist, E, KS);
        accum_slice<<<8 * BPS, 320, 0, stream>>>(elist, koff, node_embed, gacc, 0);
        accum_slice<<<8 * BPS, 320, 0, stream>>>(elist, koff, node_embed, gacc, 1);
        fc_kernel<<<NG, 320, 0, stream>>>(gacc, fc_w, fc_b, out);
    }
}

// Round 8
// 153.960 us; speedup vs baseline: 1.9493x; 1.9493x over previous
//
#include <hip/hip_runtime.h>
#include <hip/hip_bf16.h>

// Problem constants (fixed by the reference):
//   N=100000, E=500000, V=50000, NE=1000000, D=300, C=20, NG=512
#define NG 512
#define D_DIM 300
#define C_DIM 20
#define NSLICE 16
#define NBINS (NSLICE * NG)   // 8192
#define GSTRIDE 304           // padded row stride for per-slice partials
#define BPS 128               // blocks per slice per phase (x4 workers = 512 bins)
#define SC_EPB 2048           // edges per scatter block (512 thr x 4)

// ---------------- K1: in-degree + (vslice,g) histogram ----------------
__global__ __launch_bounds__(1024) void count_hist(const int* __restrict__ dst,
                                                   const int* __restrict__ src,
                                                   const int* __restrict__ nodes_batch,
                                                   const int* __restrict__ graph_ids,
                                                   int* __restrict__ cnt,
                                                   int* __restrict__ kcnt,
                                                   int E, int KS) {
    __shared__ int h[NBINS];
    int t = threadIdx.x;
    for (int i = t; i < NBINS; i += 1024) h[i] = 0;
    __syncthreads();
    for (int e = blockIdx.x * 1024 + t; e < E; e += gridDim.x * 1024) {
        int d = dst[e];
        atomicAdd(&cnt[d], 1);
        int v = nodes_batch[src[e]];
        int g = graph_ids[d];
        atomicAdd(&h[(v / KS) * NG + g], 1);
    }
    __syncthreads();
    for (int i = t; i < NBINS; i += 1024)
        if (h[i]) atomicAdd(&kcnt[i], h[i]);
}

// ---------------- K2: exclusive scan of 8192 bins (single block) ----------------
__global__ __launch_bounds__(1024) void scan8k(const int* __restrict__ kcnt,
                                               int* __restrict__ koff,
                                               int* __restrict__ kfill, int E) {
    __shared__ int s[1024];
    int t = threadIdx.x;
    int loc[8];
    int sum = 0;
#pragma unroll
    for (int i = 0; i < 8; i++) { loc[i] = sum; sum += kcnt[t * 8 + i]; }
    s[t] = sum;
    __syncthreads();
    for (int off = 1; off < 1024; off <<= 1) {
        int x = (t >= off) ? s[t - off] : 0;
        __syncthreads();
        s[t] += x;
        __syncthreads();
    }
    int base = s[t] - sum;
#pragma unroll
    for (int i = 0; i < 8; i++) {
        int val = base + loc[i];
        koff[t * 8 + i] = val;
        kfill[t * 8 + i] = val;
    }
    if (t == 1023) koff[NBINS] = E;
}

// ---------------- K3: scatter edges into (vslice,g)-sorted list ----------------
__global__ __launch_bounds__(512) void scatter8k(const int* __restrict__ src,
                                                 const int* __restrict__ dst,
                                                 const int* __restrict__ eb,
                                                 const int* __restrict__ nodes_batch,
                                                 const float* __restrict__ edge_embed,
                                                 const int* __restrict__ graph_ids,
                                                 const int* __restrict__ cnt,
                                                 int* __restrict__ kfill,
                                                 int2* __restrict__ elist, int E, int KS) {
    __shared__ int bcnt[NBINS];
    __shared__ int base[NBINS];
    int t = threadIdx.x;
    int e0 = blockIdx.x * SC_EPB;
    for (int i = t; i < NBINS; i += 512) bcnt[i] = 0;
    __syncthreads();
    int vs[SC_EPB / 512];
    float scales[SC_EPB / 512];
    int keys[SC_EPB / 512];
#pragma unroll
    for (int k = 0; k < SC_EPB / 512; k++) {
        int e = e0 + k * 512 + t;
        keys[k] = -1;
        if (e < E) {
            int d = dst[e];
            int v = nodes_batch[src[e]];
            keys[k] = (v / KS) * NG + graph_ids[d];
            vs[k] = v;
            scales[k] = edge_embed[eb[e]] / (float)max(cnt[d], 1);
            atomicAdd(&bcnt[keys[k]], 1);
        }
    }
    __syncthreads();
    for (int i = t; i < NBINS; i += 512) {
        int c = bcnt[i];
        base[i] = c ? atomicAdd(&kfill[i], c) : 0;
        bcnt[i] = 0;
    }
    __syncthreads();
#pragma unroll
    for (int k = 0; k < SC_EPB / 512; k++) {
        if (keys[k] >= 0) {
            int pos = base[keys[k]] + atomicAdd(&bcnt[keys[k]], 1);
            elist[pos] = make_int2(vs[k], __float_as_int(scales[k]));
        }
    }
}

// ---------------- K4: bin-owned accumulate, zero atomics ----------------
// phase p: slice = (bid&7) + 8p on XCD bid&7 (3.75 MB of Bmat L2-resident).
// 320 threads = 4 workers x 80 lanes; worker owns bin (slice, g) entirely:
// register-accumulates all its edges, plain-stores the 300-dim partial.
__global__ __launch_bounds__(320) void accum_bins(const int2* __restrict__ elist,
                                                  const int* __restrict__ koff,
                                                  const float* __restrict__ Bmat,
                                                  float* __restrict__ gslice, int phase) {
    int t = threadIdx.x;
    int w = t / 80, lane = t % 80;
    int slice = (blockIdx.x & 7) + 8 * phase;
    int g = ((blockIdx.x >> 3) << 2) + w;
    int bin = slice * NG + g;
    int beg = koff[bin], end = koff[bin + 1];
    if (beg >= end) return;                 // empty bin: memset supplies zeros
    bool act = lane < 75;                   // 75*4 = 300
    float ax = 0.f, ay = 0.f, az = 0.f, aw = 0.f;
#pragma unroll 8
    for (int j = beg; j < end; ++j) {
        int2 pr = elist[j];
        float s = __int_as_float(pr.y);
        if (act) {
            float4 v = ((const float4*)(Bmat + (size_t)pr.x * D_DIM))[lane];
            ax += s * v.x; ay += s * v.y; az += s * v.z; aw += s * v.w;
        }
    }
    if (act)
        ((float4*)(gslice + (size_t)bin * GSTRIDE))[lane] = make_float4(ax, ay, az, aw);
}

// ---------------- K5: reduce 16 slice-partials + ReLU + FC ----------------
__global__ __launch_bounds__(320) void fc_kernel(const float* __restrict__ gslice,
                                                 const float* __restrict__ fc_w,
                                                 const float* __restrict__ fc_b,
                                                 float* __restrict__ out) {
    __shared__ float wlds[D_DIM * C_DIM];
    __shared__ float accs[D_DIM];
    __shared__ float outs[C_DIM];
    int gid = blockIdx.x;
    int t = threadIdx.x;
    for (int i = t; i < D_DIM * C_DIM; i += 320) wlds[i] = fc_w[i];
    if (t < D_DIM) {
        float a = 0.f;
#pragma unroll
        for (int s = 0; s < NSLICE; s++)
            a += gslice[(size_t)(s * NG + gid) * GSTRIDE + t];
        accs[t] = a;
    }
    if (t < C_DIM) outs[t] = fc_b[t];
    __syncthreads();
    if (t < C_DIM * 12) {
        int c = t % C_DIM;
        int ch = t / C_DIM;
        float p = 0.f;
#pragma unroll
        for (int d = ch * 25; d < ch * 25 + 25; d++) {
            float gv = accs[d];
            gv = gv > 0.f ? gv : 0.f;
            p += gv * wlds[d * C_DIM + c];
        }
        atomicAdd(&outs[c], p);
    }
    __syncthreads();
    if (t < C_DIM) out[gid * C_DIM + t] = outs[t];
}

extern "C" void kernel_launch(void* const* d_in, const int* in_sizes, int n_in,
                              void* d_out, int out_size, void* d_ws, size_t ws_size,
                              hipStream_t stream) {
    const int* nodes_batch = (const int*)d_in[0];
    const int* edges_batch = (const int*)d_in[1];
    const int* src = (const int*)d_in[2];
    const int* dst = (const int*)d_in[3];
    const int* graph_ids = (const int*)d_in[4];
    const float* node_embed = (const float*)d_in[5];
    const float* edge_embed = (const float*)d_in[6];
    const float* fc_w = (const float*)d_in[7];
    const float* fc_b = (const float*)d_in[8];
    float* out = (float*)d_out;

    int N = in_sizes[0];
    int E = in_sizes[2];
    int K = in_sizes[5] / D_DIM;   // vocab size V
    int KS = (K + NSLICE - 1) / NSLICE;

    char* ws = (char*)d_ws;
    size_t off = 0;
    int* cnt = (int*)(ws + off); off += (size_t)N * 4;
    int* kcnt = (int*)(ws + off); off += (size_t)NBINS * 4;
    int* koff = (int*)(ws + off); off += (size_t)(NBINS + 1) * 4;
    int* kfill = (int*)(ws + off); off += (size_t)NBINS * 4;
    off = (off + 15) & ~(size_t)15;
    float* gslice = (float*)(ws + off); off += (size_t)NBINS * GSTRIDE * 4;
    int2* elist = (int2*)(ws + off); off += (size_t)E * 8;

    if (ws_size >= off) {
        hipMemsetAsync(cnt, 0, (size_t)N * 4, stream);
        hipMemsetAsync(kcnt, 0, (size_t)NBINS * 4, stream);
        hipMemsetAsync(gslice, 0, (size_t)NBINS * GSTRIDE * 4, stream);
        count_hist<<<256, 1024, 0, stream>>>(dst, src, nodes_batch, graph_ids, cnt, kcnt, E, KS);
        scan8k<<<1, 1024, 0, stream>>>(kcnt, koff, kfill, E);
        int nsb = (E + SC_EPB - 1) / SC_EPB;
        scatter8k<<<nsb, 512, 0, stream>>>(src, dst, edges_batch, nodes_batch, edge_embed,
                                           graph_ids, cnt, kfill, elist, E, KS);
        accum_bins<<<8 * BPS, 320, 0, stream>>>(elist, koff, node_embed, gslice, 0);
        accum_bins<<<8 * BPS, 320, 0, stream>>>(elist, koff, node_embed, gslice, 1);
        fc_kernel<<<NG, 320, 0, stream>>>(gslice, fc_w, fc_b, out);
    }
}

// Round 9
// 127.083 us; speedup vs baseline: 2.3615x; 1.2115x over previous
//
#include <hip/hip_runtime.h>
#include <hip/hip_bf16.h>

// Problem constants (fixed by the reference):
//   N=100000, E=500000, V=50000, NE=1000000, D=300, C=20, NG=512
#define NG 512
#define D_DIM 300
#define C_DIM 20
#define NSLICE 16
#define NBINS (NSLICE * NG)   // 8192
#define GSTRIDE 304           // padded row stride for per-slice partials
#define BPS 128               // blocks per slice per phase (x4 workers = 512 bins)
#define SC_EPB 2048           // edges per scatter block (512 thr x 4)

// ---------------- K1: in-degree + (vslice,g) histogram ----------------
__global__ __launch_bounds__(1024) void count_hist(const int* __restrict__ dst,
                                                   const int* __restrict__ src,
                                                   const int* __restrict__ nodes_batch,
                                                   const int* __restrict__ graph_ids,
                                                   int* __restrict__ cnt,
                                                   int* __restrict__ kcnt,
                                                   int E, int KS) {
    __shared__ int h[NBINS];
    int t = threadIdx.x;
    for (int i = t; i < NBINS; i += 1024) h[i] = 0;
    __syncthreads();
    for (int e = blockIdx.x * 1024 + t; e < E; e += gridDim.x * 1024) {
        int d = dst[e];
        atomicAdd(&cnt[d], 1);
        int v = nodes_batch[src[e]];
        int g = graph_ids[d];
        atomicAdd(&h[(v / KS) * NG + g], 1);
    }
    __syncthreads();
    for (int i = t; i < NBINS; i += 1024)
        if (h[i]) atomicAdd(&kcnt[i], h[i]);
}

// ---------------- K2: exclusive scan of 8192 bins (single block) ----------------
__global__ __launch_bounds__(1024) void scan8k(const int* __restrict__ kcnt,
                                               int* __restrict__ koff,
                                               int* __restrict__ kfill, int E) {
    __shared__ int s[1024];
    int t = threadIdx.x;
    int loc[8];
    int sum = 0;
#pragma unroll
    for (int i = 0; i < 8; i++) { loc[i] = sum; sum += kcnt[t * 8 + i]; }
    s[t] = sum;
    __syncthreads();
    for (int off = 1; off < 1024; off <<= 1) {
        int x = (t >= off) ? s[t - off] : 0;
        __syncthreads();
        s[t] += x;
        __syncthreads();
    }
    int base = s[t] - sum;
#pragma unroll
    for (int i = 0; i < 8; i++) {
        int val = base + loc[i];
        koff[t * 8 + i] = val;
        kfill[t * 8 + i] = val;
    }
    if (t == 1023) koff[NBINS] = E;
}

// ---------------- K3: scatter edges into (vslice,g)-sorted list ----------------
__global__ __launch_bounds__(512) void scatter8k(const int* __restrict__ src,
                                                 const int* __restrict__ dst,
                                                 const int* __restrict__ eb,
                                                 const int* __restrict__ nodes_batch,
                                                 const float* __restrict__ edge_embed,
                                                 const int* __restrict__ graph_ids,
                                                 const int* __restrict__ cnt,
                                                 int* __restrict__ kfill,
                                                 int2* __restrict__ elist, int E, int KS) {
    __shared__ int bcnt[NBINS];
    __shared__ int base[NBINS];
    int t = threadIdx.x;
    int e0 = blockIdx.x * SC_EPB;
    for (int i = t; i < NBINS; i += 512) bcnt[i] = 0;
    __syncthreads();
    int vs[SC_EPB / 512];
    float scales[SC_EPB / 512];
    int keys[SC_EPB / 512];
#pragma unroll
    for (int k = 0; k < SC_EPB / 512; k++) {
        int e = e0 + k * 512 + t;
        keys[k] = -1;
        if (e < E) {
            int d = dst[e];
            int v = nodes_batch[src[e]];
            keys[k] = (v / KS) * NG + graph_ids[d];
            vs[k] = v;
            scales[k] = edge_embed[eb[e]] / (float)max(cnt[d], 1);
            atomicAdd(&bcnt[keys[k]], 1);
        }
    }
    __syncthreads();
    for (int i = t; i < NBINS; i += 512) {
        int c = bcnt[i];
        base[i] = c ? atomicAdd(&kfill[i], c) : 0;
        bcnt[i] = 0;
    }
    __syncthreads();
#pragma unroll
    for (int k = 0; k < SC_EPB / 512; k++) {
        if (keys[k] >= 0) {
            int pos = base[keys[k]] + atomicAdd(&bcnt[keys[k]], 1);
            elist[pos] = make_int2(vs[k], __float_as_int(scales[k]));
        }
    }
}

// ---------------- K4: bin-owned accumulate, zero atomics, manual 8-deep ILP ----------------
// phase p: slice = (bid&7) + 8p on XCD bid&7 (3.75 MB of Bmat L2-resident).
// 320 threads = 4 workers x 80 lanes; worker owns bin (slice, g) entirely.
// launch_bounds(320,3): allow ~170 VGPRs so the 8 in-flight float4s stay in regs.
__global__ __launch_bounds__(320, 3) void accum_bins(const int2* __restrict__ elist,
                                                     const int* __restrict__ koff,
                                                     const float* __restrict__ Bmat,
                                                     float* __restrict__ gslice, int phase) {
    int t = threadIdx.x;
    int w = t / 80, lane = t % 80;
    if (lane >= 75) return;                 // 75*4 = 300; no predication in hot loop
    int slice = (blockIdx.x & 7) + 8 * phase;
    int g = ((blockIdx.x >> 3) << 2) + w;
    int bin = slice * NG + g;
    int beg = koff[bin], end = koff[bin + 1];
    if (beg >= end) return;                 // empty bin: memset supplies zeros

    float ax = 0.f, ay = 0.f, az = 0.f, aw = 0.f;
    int j = beg;
    for (; j + 8 <= end; j += 8) {
        int2 p0 = elist[j + 0], p1 = elist[j + 1], p2 = elist[j + 2], p3 = elist[j + 3];
        int2 p4 = elist[j + 4], p5 = elist[j + 5], p6 = elist[j + 6], p7 = elist[j + 7];
        float4 v0 = ((const float4*)(Bmat + (size_t)p0.x * D_DIM))[lane];
        float4 v1 = ((const float4*)(Bmat + (size_t)p1.x * D_DIM))[lane];
        float4 v2 = ((const float4*)(Bmat + (size_t)p2.x * D_DIM))[lane];
        float4 v3 = ((const float4*)(Bmat + (size_t)p3.x * D_DIM))[lane];
        float4 v4 = ((const float4*)(Bmat + (size_t)p4.x * D_DIM))[lane];
        float4 v5 = ((const float4*)(Bmat + (size_t)p5.x * D_DIM))[lane];
        float4 v6 = ((const float4*)(Bmat + (size_t)p6.x * D_DIM))[lane];
        float4 v7 = ((const float4*)(Bmat + (size_t)p7.x * D_DIM))[lane];
        float s0 = __int_as_float(p0.y), s1 = __int_as_float(p1.y);
        float s2 = __int_as_float(p2.y), s3 = __int_as_float(p3.y);
        float s4 = __int_as_float(p4.y), s5 = __int_as_float(p5.y);
        float s6 = __int_as_float(p6.y), s7 = __int_as_float(p7.y);
        ax += s0 * v0.x; ay += s0 * v0.y; az += s0 * v0.z; aw += s0 * v0.w;
        ax += s1 * v1.x; ay += s1 * v1.y; az += s1 * v1.z; aw += s1 * v1.w;
        ax += s2 * v2.x; ay += s2 * v2.y; az += s2 * v2.z; aw += s2 * v2.w;
        ax += s3 * v3.x; ay += s3 * v3.y; az += s3 * v3.z; aw += s3 * v3.w;
        ax += s4 * v4.x; ay += s4 * v4.y; az += s4 * v4.z; aw += s4 * v4.w;
        ax += s5 * v5.x; ay += s5 * v5.y; az += s5 * v5.z; aw += s5 * v5.w;
        ax += s6 * v6.x; ay += s6 * v6.y; az += s6 * v6.z; aw += s6 * v6.w;
        ax += s7 * v7.x; ay += s7 * v7.y; az += s7 * v7.z; aw += s7 * v7.w;
    }
    // remainder (<8 edges), 4-deep then scalar
    for (; j + 4 <= end; j += 4) {
        int2 p0 = elist[j + 0], p1 = elist[j + 1], p2 = elist[j + 2], p3 = elist[j + 3];
        float4 v0 = ((const float4*)(Bmat + (size_t)p0.x * D_DIM))[lane];
        float4 v1 = ((const float4*)(Bmat + (size_t)p1.x * D_DIM))[lane];
        float4 v2 = ((const float4*)(Bmat + (size_t)p2.x * D_DIM))[lane];
        float4 v3 = ((const float4*)(Bmat + (size_t)p3.x * D_DIM))[lane];
        float s0 = __int_as_float(p0.y), s1 = __int_as_float(p1.y);
        float s2 = __int_as_float(p2.y), s3 = __int_as_float(p3.y);
        ax += s0 * v0.x; ay += s0 * v0.y; az += s0 * v0.z; aw += s0 * v0.w;
        ax += s1 * v1.x; ay += s1 * v1.y; az += s1 * v1.z; aw += s1 * v1.w;
        ax += s2 * v2.x; ay += s2 * v2.y; az += s2 * v2.z; aw += s2 * v2.w;
        ax += s3 * v3.x; ay += s3 * v3.y; az += s3 * v3.z; aw += s3 * v3.w;
    }
    for (; j < end; ++j) {
        int2 pr = elist[j];
        float s = __int_as_float(pr.y);
        float4 v = ((const float4*)(Bmat + (size_t)pr.x * D_DIM))[lane];
        ax += s * v.x; ay += s * v.y; az += s * v.z; aw += s * v.w;
    }
    ((float4*)(gslice + (size_t)bin * GSTRIDE))[lane] = make_float4(ax, ay, az, aw);
}

// ---------------- K5: reduce 16 slice-partials + ReLU + FC ----------------
__global__ __launch_bounds__(320) void fc_kernel(const float* __restrict__ gslice,
                                                 const float* __restrict__ fc_w,
                                                 const float* __restrict__ fc_b,
                                                 float* __restrict__ out) {
    __shared__ float wlds[D_DIM * C_DIM];
    __shared__ float accs[D_DIM];
    __shared__ float outs[C_DIM];
    int gid = blockIdx.x;
    int t = threadIdx.x;
    for (int i = t; i < D_DIM * C_DIM; i += 320) wlds[i] = fc_w[i];
    if (t < D_DIM) {
        float a = 0.f;
#pragma unroll
        for (int s = 0; s < NSLICE; s++)
            a += gslice[(size_t)(s * NG + gid) * GSTRIDE + t];
        accs[t] = a;
    }
    if (t < C_DIM) outs[t] = fc_b[t];
    __syncthreads();
    if (t < C_DIM * 12) {
        int c = t % C_DIM;
        int ch = t / C_DIM;
        float p = 0.f;
#pragma unroll
        for (int d = ch * 25; d < ch * 25 + 25; d++) {
            float gv = accs[d];
            gv = gv > 0.f ? gv : 0.f;
            p += gv * wlds[d * C_DIM + c];
        }
        atomicAdd(&outs[c], p);
    }
    __syncthreads();
    if (t < C_DIM) out[gid * C_DIM + t] = outs[t];
}

extern "C" void kernel_launch(void* const* d_in, const int* in_sizes, int n_in,
                              void* d_out, int out_size, void* d_ws, size_t ws_size,
                              hipStream_t stream) {
    const int* nodes_batch = (const int*)d_in[0];
    const int* edges_batch = (const int*)d_in[1];
    const int* src = (const int*)d_in[2];
    const int* dst = (const int*)d_in[3];
    const int* graph_ids = (const int*)d_in[4];
    const float* node_embed = (const float*)d_in[5];
    const float* edge_embed = (const float*)d_in[6];
    const float* fc_w = (const float*)d_in[7];
    const float* fc_b = (const float*)d_in[8];
    float* out = (float*)d_out;

    int N = in_sizes[0];
    int E = in_sizes[2];
    int K = in_sizes[5] / D_DIM;   // vocab size V
    int KS = (K + NSLICE - 1) / NSLICE;

    char* ws = (char*)d_ws;
    size_t off = 0;
    int* cnt = (int*)(ws + off); off += (size_t)N * 4;
    int* kcnt = (int*)(ws + off); off += (size_t)NBINS * 4;
    int* koff = (int*)(ws + off); off += (size_t)(NBINS + 1) * 4;
    int* kfill = (int*)(ws + off); off += (size_t)NBINS * 4;
    off = (off + 15) & ~(size_t)15;
    float* gslice = (float*)(ws + off); off += (size_t)NBINS * GSTRIDE * 4;
    int2* elist = (int2*)(ws + off); off += (size_t)E * 8;

    if (ws_size >= off) {
        hipMemsetAsync(cnt, 0, (size_t)N * 4, stream);
        hipMemsetAsync(kcnt, 0, (size_t)NBINS * 4, stream);
        hipMemsetAsync(gslice, 0, (size_t)NBINS * GSTRIDE * 4, stream);
        count_hist<<<256, 1024, 0, stream>>>(dst, src, nodes_batch, graph_ids, cnt, kcnt, E, KS);
        scan8k<<<1, 1024, 0, stream>>>(kcnt, koff, kfill, E);
        int nsb = (E + SC_EPB - 1) / SC_EPB;
        scatter8k<<<nsb, 512, 0, stream>>>(src, dst, edges_batch, nodes_batch, edge_embed,
                                           graph_ids, cnt, kfill, elist, E, KS);
        accum_bins<<<8 * BPS, 320, 0, stream>>>(elist, koff, node_embed, gslice, 0);
        accum_bins<<<8 * BPS, 320, 0, stream>>>(elist, koff, node_embed, gslice, 1);
        fc_kernel<<<NG, 320, 0, stream>>>(gslice, fc_w, fc_b, out);
    }
}

// Round 10
// 117.548 us; speedup vs baseline: 2.5531x; 1.0811x over previous
//
#include <hip/hip_runtime.h>
#include <hip/hip_bf16.h>

// Problem constants (fixed by the reference):
//   N=100000, E=500000, V=50000, NE=1000000, D=300, C=20, NG=512
#define NG 512
#define D_DIM 300
#define C_DIM 20
#define NSLICE 8
#define NBINS (NSLICE * NG)   // 4096
#define GSTRIDE 304           // padded row stride (elems) for B16 and gslice
#define SC_EPB 2048           // edges per scatter block (512 thr x 4)

static __device__ inline ushort f2bf(float f) {
    union { float f; unsigned u; } x; x.f = f;
    unsigned r = x.u + 0x7FFF + ((x.u >> 16) & 1);   // RNE
    return (ushort)(r >> 16);
}

// ---------------- K0: convert node_embed f32[K][300] -> bf16[K][304] ----------------
__global__ __launch_bounds__(256) void convert_b(const float* __restrict__ B,
                                                 ushort* __restrict__ B16, int K) {
    int total = K * 38;
    for (int idx = blockIdx.x * 256 + threadIdx.x; idx < total; idx += gridDim.x * 256) {
        int row = idx / 38;
        int k = idx - row * 38;
        int d0 = k * 8;
        const float* p = B + (size_t)row * D_DIM + d0;
        float f0, f1, f2, f3, f4, f5, f6, f7;
        if (d0 + 8 <= D_DIM) {
            float4 a = *(const float4*)p;
            float4 b = *(const float4*)(p + 4);
            f0 = a.x; f1 = a.y; f2 = a.z; f3 = a.w;
            f4 = b.x; f5 = b.y; f6 = b.z; f7 = b.w;
        } else {                      // k == 37: dims 296..299 valid, 300..303 pad
            float4 a = *(const float4*)p;
            f0 = a.x; f1 = a.y; f2 = a.z; f3 = a.w;
            f4 = f5 = f6 = f7 = 0.f;
        }
        uint4 pk;
        pk.x = (unsigned)f2bf(f0) | ((unsigned)f2bf(f1) << 16);
        pk.y = (unsigned)f2bf(f2) | ((unsigned)f2bf(f3) << 16);
        pk.z = (unsigned)f2bf(f4) | ((unsigned)f2bf(f5) << 16);
        pk.w = (unsigned)f2bf(f6) | ((unsigned)f2bf(f7) << 16);
        *(uint4*)(B16 + (size_t)row * GSTRIDE + d0) = pk;
    }
}

// ---------------- K1: in-degree + (vslice,g) histogram ----------------
__global__ __launch_bounds__(1024) void count_hist(const int* __restrict__ dst,
                                                   const int* __restrict__ src,
                                                   const int* __restrict__ nodes_batch,
                                                   const int* __restrict__ graph_ids,
                                                   int* __restrict__ cnt,
                                                   int* __restrict__ kcnt,
                                                   int E, int KS) {
    __shared__ int h[NBINS];
    int t = threadIdx.x;
    for (int i = t; i < NBINS; i += 1024) h[i] = 0;
    __syncthreads();
    for (int e = blockIdx.x * 1024 + t; e < E; e += gridDim.x * 1024) {
        int d = dst[e];
        atomicAdd(&cnt[d], 1);
        int v = nodes_batch[src[e]];
        int g = graph_ids[d];
        atomicAdd(&h[(v / KS) * NG + g], 1);
    }
    __syncthreads();
    for (int i = t; i < NBINS; i += 1024)
        if (h[i]) atomicAdd(&kcnt[i], h[i]);
}

// ---------------- K2: exclusive scan of 4096 bins (single block) ----------------
__global__ __launch_bounds__(1024) void scan4k(const int* __restrict__ kcnt,
                                               int* __restrict__ koff,
                                               int* __restrict__ kfill, int E) {
    __shared__ int s[1024];
    int t = threadIdx.x;
    int l0 = kcnt[t * 4 + 0], l1 = kcnt[t * 4 + 1], l2 = kcnt[t * 4 + 2], l3 = kcnt[t * 4 + 3];
    int sum = l0 + l1 + l2 + l3;
    s[t] = sum;
    __syncthreads();
    for (int off = 1; off < 1024; off <<= 1) {
        int x = (t >= off) ? s[t - off] : 0;
        __syncthreads();
        s[t] += x;
        __syncthreads();
    }
    int base = s[t] - sum;
    int v0 = base, v1 = base + l0, v2 = base + l0 + l1, v3 = base + l0 + l1 + l2;
    koff[t * 4 + 0] = v0; kfill[t * 4 + 0] = v0;
    koff[t * 4 + 1] = v1; kfill[t * 4 + 1] = v1;
    koff[t * 4 + 2] = v2; kfill[t * 4 + 2] = v2;
    koff[t * 4 + 3] = v3; kfill[t * 4 + 3] = v3;
    if (t == 1023) koff[NBINS] = E;
}

// ---------------- K3: scatter edges into (vslice,g)-sorted list ----------------
__global__ __launch_bounds__(512) void scatter4k(const int* __restrict__ src,
                                                 const int* __restrict__ dst,
                                                 const int* __restrict__ eb,
                                                 const int* __restrict__ nodes_batch,
                                                 const float* __restrict__ edge_embed,
                                                 const int* __restrict__ graph_ids,
                                                 const int* __restrict__ cnt,
                                                 int* __restrict__ kfill,
                                                 int2* __restrict__ elist, int E, int KS) {
    __shared__ int bcnt[NBINS];
    __shared__ int base[NBINS];
    int t = threadIdx.x;
    int e0 = blockIdx.x * SC_EPB;
    for (int i = t; i < NBINS; i += 512) bcnt[i] = 0;
    __syncthreads();
    int vs[SC_EPB / 512];
    float scales[SC_EPB / 512];
    int keys[SC_EPB / 512];
#pragma unroll
    for (int k = 0; k < SC_EPB / 512; k++) {
        int e = e0 + k * 512 + t;
        keys[k] = -1;
        if (e < E) {
            int d = dst[e];
            int v = nodes_batch[src[e]];
            keys[k] = (v / KS) * NG + graph_ids[d];
            vs[k] = v;
            scales[k] = edge_embed[eb[e]] / (float)max(cnt[d], 1);
            atomicAdd(&bcnt[keys[k]], 1);
        }
    }
    __syncthreads();
    for (int i = t; i < NBINS; i += 512) {
        int c = bcnt[i];
        base[i] = c ? atomicAdd(&kfill[i], c) : 0;
        bcnt[i] = 0;
    }
    __syncthreads();
#pragma unroll
    for (int k = 0; k < SC_EPB / 512; k++) {
        if (keys[k] >= 0) {
            int pos = base[keys[k]] + atomicAdd(&bcnt[keys[k]], 1);
            elist[pos] = make_int2(vs[k], __float_as_int(scales[k]));
        }
    }
}

// ---------------- K4: wave-per-bin accumulate, bf16 rows, zero atomics, one phase ----------------
// slice = bid&7 pinned to XCD bid&7 (3.8 MB bf16 slice L2-resident).
// 256 threads = 4 waves; wave owns bin (slice, g): lanes 0..37 each own 8 dims (16B).
static __device__ inline void acc8(uint4 q, float s, float* a) {
    a[0] += s * __uint_as_float(q.x << 16);
    a[1] += s * __uint_as_float(q.x & 0xFFFF0000u);
    a[2] += s * __uint_as_float(q.y << 16);
    a[3] += s * __uint_as_float(q.y & 0xFFFF0000u);
    a[4] += s * __uint_as_float(q.z << 16);
    a[5] += s * __uint_as_float(q.z & 0xFFFF0000u);
    a[6] += s * __uint_as_float(q.w << 16);
    a[7] += s * __uint_as_float(q.w & 0xFFFF0000u);
}

__global__ __launch_bounds__(256, 4) void accum_wave(const int2* __restrict__ elist,
                                                     const int* __restrict__ koff,
                                                     const ushort* __restrict__ B16,
                                                     float* __restrict__ gslice) {
    int t = threadIdx.x;
    int wv = t >> 6, lane = t & 63;
    if (lane >= 38) return;                 // 38*8 = 304 dims
    int slice = blockIdx.x & 7;
    int g = ((blockIdx.x >> 3) << 2) + wv;
    int bin = slice * NG + g;
    int beg = koff[bin], end = koff[bin + 1];
    const ushort* Bl = B16 + (lane << 3);

    float a[8] = {0.f, 0.f, 0.f, 0.f, 0.f, 0.f, 0.f, 0.f};
    int j = beg;
    for (; j + 8 <= end; j += 8) {
        int2 p0 = elist[j + 0], p1 = elist[j + 1], p2 = elist[j + 2], p3 = elist[j + 3];
        int2 p4 = elist[j + 4], p5 = elist[j + 5], p6 = elist[j + 6], p7 = elist[j + 7];
        uint4 q0 = *(const uint4*)(Bl + (size_t)p0.x * GSTRIDE);
        uint4 q1 = *(const uint4*)(Bl + (size_t)p1.x * GSTRIDE);
        uint4 q2 = *(const uint4*)(Bl + (size_t)p2.x * GSTRIDE);
        uint4 q3 = *(const uint4*)(Bl + (size_t)p3.x * GSTRIDE);
        uint4 q4 = *(const uint4*)(Bl + (size_t)p4.x * GSTRIDE);
        uint4 q5 = *(const uint4*)(Bl + (size_t)p5.x * GSTRIDE);
        uint4 q6 = *(const uint4*)(Bl + (size_t)p6.x * GSTRIDE);
        uint4 q7 = *(const uint4*)(Bl + (size_t)p7.x * GSTRIDE);
        acc8(q0, __int_as_float(p0.y), a);
        acc8(q1, __int_as_float(p1.y), a);
        acc8(q2, __int_as_float(p2.y), a);
        acc8(q3, __int_as_float(p3.y), a);
        acc8(q4, __int_as_float(p4.y), a);
        acc8(q5, __int_as_float(p5.y), a);
        acc8(q6, __int_as_float(p6.y), a);
        acc8(q7, __int_as_float(p7.y), a);
    }
    for (; j + 4 <= end; j += 4) {
        int2 p0 = elist[j + 0], p1 = elist[j + 1], p2 = elist[j + 2], p3 = elist[j + 3];
        uint4 q0 = *(const uint4*)(Bl + (size_t)p0.x * GSTRIDE);
        uint4 q1 = *(const uint4*)(Bl + (size_t)p1.x * GSTRIDE);
        uint4 q2 = *(const uint4*)(Bl + (size_t)p2.x * GSTRIDE);
        uint4 q3 = *(const uint4*)(Bl + (size_t)p3.x * GSTRIDE);
        acc8(q0, __int_as_float(p0.y), a);
        acc8(q1, __int_as_float(p1.y), a);
        acc8(q2, __int_as_float(p2.y), a);
        acc8(q3, __int_as_float(p3.y), a);
    }
    for (; j < end; ++j) {
        int2 pr = elist[j];
        uint4 q = *(const uint4*)(Bl + (size_t)pr.x * GSTRIDE);
        acc8(q, __int_as_float(pr.y), a);
    }
    // always store (empty bins write zeros -> no gslice memset needed)
    float4* outp = (float4*)(gslice + (size_t)bin * GSTRIDE + (lane << 3));
    outp[0] = make_float4(a[0], a[1], a[2], a[3]);
    outp[1] = make_float4(a[4], a[5], a[6], a[7]);
}

// ---------------- K5: reduce 8 slice-partials + ReLU + FC ----------------
__global__ __launch_bounds__(320) void fc_kernel(const float* __restrict__ gslice,
                                                 const float* __restrict__ fc_w,
                                                 const float* __restrict__ fc_b,
                                                 float* __restrict__ out) {
    __shared__ float wlds[D_DIM * C_DIM];
    __shared__ float accs[D_DIM];
    __shared__ float outs[C_DIM];
    int gid = blockIdx.x;
    int t = threadIdx.x;
    for (int i = t; i < D_DIM * C_DIM; i += 320) wlds[i] = fc_w[i];
    if (t < D_DIM) {
        float a = 0.f;
#pragma unroll
        for (int s = 0; s < NSLICE; s++)
            a += gslice[(size_t)(s * NG + gid) * GSTRIDE + t];
        accs[t] = a;
    }
    if (t < C_DIM) outs[t] = fc_b[t];
    __syncthreads();
    if (t < C_DIM * 12) {
        int c = t % C_DIM;
        int ch = t / C_DIM;
        float p = 0.f;
#pragma unroll
        for (int d = ch * 25; d < ch * 25 + 25; d++) {
            float gv = accs[d];
            gv = gv > 0.f ? gv : 0.f;
            p += gv * wlds[d * C_DIM + c];
        }
        atomicAdd(&outs[c], p);
    }
    __syncthreads();
    if (t < C_DIM) out[gid * C_DIM + t] = outs[t];
}

extern "C" void kernel_launch(void* const* d_in, const int* in_sizes, int n_in,
                              void* d_out, int out_size, void* d_ws, size_t ws_size,
                              hipStream_t stream) {
    const int* nodes_batch = (const int*)d_in[0];
    const int* edges_batch = (const int*)d_in[1];
    const int* src = (const int*)d_in[2];
    const int* dst = (const int*)d_in[3];
    const int* graph_ids = (const int*)d_in[4];
    const float* node_embed = (const float*)d_in[5];
    const float* edge_embed = (const float*)d_in[6];
    const float* fc_w = (const float*)d_in[7];
    const float* fc_b = (const float*)d_in[8];
    float* out = (float*)d_out;

    int N = in_sizes[0];
    int E = in_sizes[2];
    int K = in_sizes[5] / D_DIM;   // vocab size V
    int KS = (K + NSLICE - 1) / NSLICE;

    char* ws = (char*)d_ws;
    size_t off = 0;
    int* cnt = (int*)(ws + off); off += (size_t)N * 4;
    int* kcnt = (int*)(ws + off); off += (size_t)NBINS * 4;
    int* koff = (int*)(ws + off); off += (size_t)(NBINS + 1) * 4;
    int* kfill = (int*)(ws + off); off += (size_t)NBINS * 4;
    off = (off + 15) & ~(size_t)15;
    ushort* B16 = (ushort*)(ws + off); off += (size_t)K * GSTRIDE * 2;
    float* gslice = (float*)(ws + off); off += (size_t)NBINS * GSTRIDE * 4;
    int2* elist = (int2*)(ws + off); off += (size_t)E * 8;

    if (ws_size >= off) {
        hipMemsetAsync(cnt, 0, (size_t)N * 4, stream);
        hipMemsetAsync(kcnt, 0, (size_t)NBINS * 4, stream);
        convert_b<<<2048, 256, 0, stream>>>(node_embed, B16, K);
        count_hist<<<256, 1024, 0, stream>>>(dst, src, nodes_batch, graph_ids, cnt, kcnt, E, KS);
        scan4k<<<1, 1024, 0, stream>>>(kcnt, koff, kfill, E);
        int nsb = (E + SC_EPB - 1) / SC_EPB;
        scatter4k<<<nsb, 512, 0, stream>>>(src, dst, edges_batch, nodes_batch, edge_embed,
                                           graph_ids, cnt, kfill, elist, E, KS);
        accum_wave<<<8 * (NG / 4), 256, 0, stream>>>(elist, koff, B16, gslice);
        fc_kernel<<<NG, 320, 0, stream>>>(gslice, fc_w, fc_b, out);
    }
}